// Round 1
// baseline (389.725 us; speedup 1.0000x reference)
//
#include <hip/hip_runtime.h>

typedef short short8 __attribute__((ext_vector_type(8)));
typedef float f32x4 __attribute__((ext_vector_type(4)));

#define D_FEAT 256
#define P_TOK  64

// ---- LDS layout (ushort units) ----
// xb:    [64][264]  @ 0       (x staging, later attn_out)   16896
// q:     [64][264]  @ 16896                                  16896
// k:     [64][264]  @ 33792                                  16896
//   (q+k region reused as probs: 8 waves x [64][72] = 36864 @ 16896)
// vT:    [256][72]  @ 53760                                  18432
#define XB_OFF 0
#define Q_OFF  16896
#define K_OFF  33792
#define PR_OFF 16896
#define VT_OFF 53760
#define LDS_TOT 72192   // ushorts = 144384 B
#define ST264 264
#define ST72  72

static __device__ __forceinline__ unsigned short f2b(float f) {
  union { float f; unsigned u; } v; v.f = f;
  unsigned r = v.u + 0x7FFFu + ((v.u >> 16) & 1u);  // RNE
  return (unsigned short)(r >> 16);
}

// ---------------- prep: W -> bf16 B-fragment layout ----------------
// Wf[(nt*8+ks)*64 + lane][j] = bf16( W[ks*32 + (lane>>4)*8 + j][nt*16 + (lane&15)] )
__global__ void prep_w_kernel(const float* __restrict__ W, unsigned short* __restrict__ Wf,
                              int ncols, int total) {
  const int tid = blockIdx.x * blockDim.x + threadIdx.x;
  if (tid >= total) return;
  const int l  = tid & 63;
  const int ks = (tid >> 6) & 7;
  const int nt = tid >> 9;
  const int n  = nt * 16 + (l & 15);
  const int k0 = ks * 32 + (l >> 4) * 8;
  short8 v;
#pragma unroll
  for (int j = 0; j < 8; ++j) v[j] = (short)f2b(W[(size_t)(k0 + j) * ncols + n]);
  *reinterpret_cast<short8*>(&Wf[(size_t)tid * 8]) = v;
}

// ---------------- prep: bias_table[rel_index] -> C-fragment layout ----------------
// bc[((h*16 + mt*4+nt)*64 + lane)*4 + i] = bt[ri[r*64+c]*8 + h],
//   r = mt*16 + (lane>>4)*4 + i, c = nt*16 + (lane&15)
__global__ void prep_bias_kernel(const float* __restrict__ bt, const int* __restrict__ ri,
                                 float* __restrict__ bc) {
  const int tid = blockIdx.x * blockDim.x + threadIdx.x;
  if (tid >= 8192) return;
  const int l  = tid & 63;
  const int t  = (tid >> 6) & 15;
  const int h  = tid >> 10;
  const int mt = t >> 2, nt = t & 3;
  f32x4 v;
#pragma unroll
  for (int i = 0; i < 4; ++i) {
    const int r = mt * 16 + (l >> 4) * 4 + i;
    const int c = nt * 16 + (l & 15);
    v[i] = bt[ri[r * 64 + c] * 8 + h];
  }
  *reinterpret_cast<f32x4*>(&bc[(size_t)tid * 4]) = v;
}

// ---------------- main: one workgroup per window ----------------
__global__ __launch_bounds__(512, 2)
void win_attn_kernel(const float* __restrict__ x,
                     const float* __restrict__ bqkv,
                     const float* __restrict__ bm,
                     const unsigned short* __restrict__ Wqkv_f,
                     const unsigned short* __restrict__ Wm_f,
                     const float* __restrict__ bias_c,
                     float* __restrict__ out)
{
  __shared__ unsigned short sm[LDS_TOT];
  const int tid = threadIdx.x;
  const int w   = tid >> 6;   // wave id == head id
  const int l   = tid & 63;
  const int lr  = l & 15;     // col-lane within 16
  const int lg  = l >> 4;     // k-group 0..3
  const long long win = blockIdx.x;
  const float* xw = x + win * (P_TOK * D_FEAT);

  // ---- stage x -> bf16 LDS [64][264] ----
#pragma unroll
  for (int it = 0; it < 8; ++it) {
    const int f = it * 2048 + tid * 4;
    const int row = f >> 8, col = f & 255;
    const float4 v = *reinterpret_cast<const float4*>(xw + f);
    ushort4 b;
    b.x = f2b(v.x); b.y = f2b(v.y); b.z = f2b(v.z); b.w = f2b(v.w);
    *reinterpret_cast<ushort4*>(&sm[XB_OFF + row * ST264 + col]) = b;
  }
  __syncthreads();

  // ---- phase A: qkv = x @ Wqkv + bqkv; wave w owns cols [96w, 96w+96) ----
  {
    f32x4 acc[4][6];
    float bq[6];
#pragma unroll
    for (int t = 0; t < 6; ++t) bq[t] = bqkv[w * 96 + t * 16 + lr];
#pragma unroll
    for (int mt = 0; mt < 4; ++mt)
#pragma unroll
      for (int t = 0; t < 6; ++t)
        acc[mt][t] = (f32x4){bq[t], bq[t], bq[t], bq[t]};

#pragma unroll
    for (int ks = 0; ks < 8; ++ks) {
      short8 a[4];
#pragma unroll
      for (int mt = 0; mt < 4; ++mt)
        a[mt] = *reinterpret_cast<const short8*>(
            &sm[XB_OFF + (lr + 16 * mt) * ST264 + lg * 8 + ks * 32]);
#pragma unroll
      for (int t = 0; t < 6; ++t) {
        const short8 bf = *reinterpret_cast<const short8*>(
            &Wqkv_f[(size_t)(((w * 6 + t) * 8 + ks) * 64 + l) * 8]);
#pragma unroll
        for (int mt = 0; mt < 4; ++mt)
          acc[mt][t] = __builtin_amdgcn_mfma_f32_16x16x32_bf16(a[mt], bf, acc[mt][t], 0, 0, 0);
      }
    }

    // scatter to q (row-major), k (row-major, pre-scaled), vT (transposed, packed)
#pragma unroll
    for (int t = 0; t < 6; ++t) {
      const int col = w * 96 + t * 16 + lr;
      if (col < 256) {
#pragma unroll
        for (int mt = 0; mt < 4; ++mt)
#pragma unroll
          for (int i = 0; i < 4; ++i)
            sm[Q_OFF + (16 * mt + lg * 4 + i) * ST264 + col] = f2b(acc[mt][t][i]);
      } else if (col < 512) {
        const int c = col - 256;
#pragma unroll
        for (int mt = 0; mt < 4; ++mt)
#pragma unroll
          for (int i = 0; i < 4; ++i)
            sm[K_OFF + (16 * mt + lg * 4 + i) * ST264 + c] = f2b(acc[mt][t][i] * 0.0625f);
      } else {
        const int c = col - 512;
#pragma unroll
        for (int mt = 0; mt < 4; ++mt) {
          ushort4 b;
          b.x = f2b(acc[mt][t][0]); b.y = f2b(acc[mt][t][1]);
          b.z = f2b(acc[mt][t][2]); b.w = f2b(acc[mt][t][3]);
          *reinterpret_cast<ushort4*>(&sm[VT_OFF + c * ST72 + 16 * mt + lg * 4]) = b;
        }
      }
    }
  }
  __syncthreads();

  // ---- phase B: attention, wave w = head w (q/k cols [32w, 32w+32)) ----
  short8 qf[4], kf[4];
#pragma unroll
  for (int mt = 0; mt < 4; ++mt)
    qf[mt] = *reinterpret_cast<const short8*>(
        &sm[Q_OFF + (lr + 16 * mt) * ST264 + w * 32 + lg * 8]);
#pragma unroll
  for (int nt = 0; nt < 4; ++nt)
    kf[nt] = *reinterpret_cast<const short8*>(
        &sm[K_OFF + (lr + 16 * nt) * ST264 + w * 32 + lg * 8]);
  __syncthreads();  // q/k region now free -> probs scratch

  // scores (+bias via accumulator init)
  f32x4 s[4][4];
#pragma unroll
  for (int mt = 0; mt < 4; ++mt)
#pragma unroll
    for (int nt = 0; nt < 4; ++nt) {
      const f32x4 bb = *reinterpret_cast<const f32x4*>(
          &bias_c[(size_t)((w * 16 + mt * 4 + nt) * 64 + l) * 4]);
      s[mt][nt] = __builtin_amdgcn_mfma_f32_16x16x32_bf16(qf[mt], kf[nt], bb, 0, 0, 0);
    }

  // wave-parallel softmax over keys: 4 nt regs + 16 lanes of group
  float rmax[4][4], rinv[4][4];
#pragma unroll
  for (int mt = 0; mt < 4; ++mt)
#pragma unroll
    for (int i = 0; i < 4; ++i) {
      float m = fmaxf(fmaxf(s[mt][0][i], s[mt][1][i]), fmaxf(s[mt][2][i], s[mt][3][i]));
      m = fmaxf(m, __shfl_xor(m, 1));
      m = fmaxf(m, __shfl_xor(m, 2));
      m = fmaxf(m, __shfl_xor(m, 4));
      m = fmaxf(m, __shfl_xor(m, 8));
      rmax[mt][i] = m;
    }
#pragma unroll
  for (int mt = 0; mt < 4; ++mt)
#pragma unroll
    for (int nt = 0; nt < 4; ++nt)
#pragma unroll
      for (int i = 0; i < 4; ++i)
        s[mt][nt][i] = __expf(s[mt][nt][i] - rmax[mt][i]);
#pragma unroll
  for (int mt = 0; mt < 4; ++mt)
#pragma unroll
    for (int i = 0; i < 4; ++i) {
      float sum = s[mt][0][i] + s[mt][1][i] + s[mt][2][i] + s[mt][3][i];
      sum += __shfl_xor(sum, 1);
      sum += __shfl_xor(sum, 2);
      sum += __shfl_xor(sum, 4);
      sum += __shfl_xor(sum, 8);
      rinv[mt][i] = 1.0f / sum;
    }

  // probs -> per-wave LDS scratch (bf16, stride 72)
  const int prb = PR_OFF + w * 4608;
#pragma unroll
  for (int mt = 0; mt < 4; ++mt)
#pragma unroll
    for (int nt = 0; nt < 4; ++nt)
#pragma unroll
      for (int i = 0; i < 4; ++i)
        sm[prb + (16 * mt + lg * 4 + i) * ST72 + nt * 16 + lr] = f2b(s[mt][nt][i]);

  // PV: out[i][d] = sum_j P[i][j] * v[j][d]
  f32x4 o[4][2];
#pragma unroll
  for (int mt = 0; mt < 4; ++mt)
#pragma unroll
    for (int nt = 0; nt < 2; ++nt)
      o[mt][nt] = (f32x4){0.f, 0.f, 0.f, 0.f};
#pragma unroll
  for (int kh = 0; kh < 2; ++kh) {
    short8 pa[4];
#pragma unroll
    for (int mt = 0; mt < 4; ++mt)
      pa[mt] = *reinterpret_cast<const short8*>(
          &sm[prb + (lr + 16 * mt) * ST72 + lg * 8 + kh * 32]);
#pragma unroll
    for (int nt = 0; nt < 2; ++nt) {
      const short8 vb = *reinterpret_cast<const short8*>(
          &sm[VT_OFF + (w * 32 + nt * 16 + lr) * ST72 + lg * 8 + kh * 32]);
#pragma unroll
      for (int mt = 0; mt < 4; ++mt)
        o[mt][nt] = __builtin_amdgcn_mfma_f32_16x16x32_bf16(pa[mt], vb, o[mt][nt], 0, 0, 0);
    }
  }

  // normalize rows, attn_out -> XB region (bf16 row-major [64][264])
#pragma unroll
  for (int mt = 0; mt < 4; ++mt)
#pragma unroll
    for (int nt = 0; nt < 2; ++nt)
#pragma unroll
      for (int i = 0; i < 4; ++i)
        sm[XB_OFF + (16 * mt + lg * 4 + i) * ST264 + w * 32 + nt * 16 + lr] =
            f2b(o[mt][nt][i] * rinv[mt][i]);
  __syncthreads();

  // ---- phase C: out = attn_out @ Wm + bm; wave w owns cols [32w, 32w+32) ----
  f32x4 po[4][2];
  {
    float bmv[2];
#pragma unroll
    for (int nt = 0; nt < 2; ++nt) bmv[nt] = bm[w * 32 + nt * 16 + lr];
#pragma unroll
    for (int mt = 0; mt < 4; ++mt)
#pragma unroll
      for (int nt = 0; nt < 2; ++nt)
        po[mt][nt] = (f32x4){bmv[nt], bmv[nt], bmv[nt], bmv[nt]};
  }
#pragma unroll
  for (int ks = 0; ks < 8; ++ks) {
    short8 a[4];
#pragma unroll
    for (int mt = 0; mt < 4; ++mt)
      a[mt] = *reinterpret_cast<const short8*>(
          &sm[XB_OFF + (lr + 16 * mt) * ST264 + lg * 8 + ks * 32]);
#pragma unroll
    for (int nt = 0; nt < 2; ++nt) {
      const short8 bf = *reinterpret_cast<const short8*>(
          &Wm_f[(size_t)(((w * 2 + nt) * 8 + ks) * 64 + l) * 8]);
#pragma unroll
      for (int mt = 0; mt < 4; ++mt)
        po[mt][nt] = __builtin_amdgcn_mfma_f32_16x16x32_bf16(a[mt], bf, po[mt][nt], 0, 0, 0);
    }
  }

  float* ow = out + win * (P_TOK * D_FEAT);
#pragma unroll
  for (int mt = 0; mt < 4; ++mt)
#pragma unroll
    for (int nt = 0; nt < 2; ++nt)
#pragma unroll
      for (int i = 0; i < 4; ++i)
        ow[(16 * mt + lg * 4 + i) * 256 + w * 32 + nt * 16 + lr] = po[mt][nt][i];
}

extern "C" void kernel_launch(void* const* d_in, const int* in_sizes, int n_in,
                              void* d_out, int out_size, void* d_ws, size_t ws_size,
                              hipStream_t stream) {
  const float* x    = (const float*)d_in[0];
  const float* Wqkv = (const float*)d_in[1];
  const float* bqkv = (const float*)d_in[2];
  const float* Wm   = (const float*)d_in[3];
  const float* bm   = (const float*)d_in[4];
  const float* bt   = (const float*)d_in[5];
  const int*   ri   = (const int*)d_in[6];

  // workspace layout: Wqkv_f 393216 B | Wm_f 131072 B | bias_c 131072 B
  unsigned short* Wqkv_f = (unsigned short*)d_ws;
  unsigned short* Wm_f   = (unsigned short*)((char*)d_ws + 393216);
  float*          bias_c = (float*)((char*)d_ws + 524288);

  prep_w_kernel<<<48, 512, 0, stream>>>(Wqkv, Wqkv_f, 768, 24576);
  prep_w_kernel<<<16, 512, 0, stream>>>(Wm, Wm_f, 256, 8192);
  prep_bias_kernel<<<16, 512, 0, stream>>>(bt, ri, bias_c);

  const int nwin = in_sizes[0] / (P_TOK * D_FEAT);  // 4096
  win_attn_kernel<<<nwin, 512, 0, stream>>>(x, bqkv, bm, Wqkv_f, Wm_f, bias_c, (float*)d_out);
}

// Round 2
// 262.087 us; speedup vs baseline: 1.4870x; 1.4870x over previous
//
#include <hip/hip_runtime.h>

typedef short short8 __attribute__((ext_vector_type(8)));
typedef float f32x4 __attribute__((ext_vector_type(4)));

#define D_FEAT 256
#define P_TOK  64

// ---- LDS layout (ushort units) ----
// xb:      [64][264] @ 0           16896 ushorts (x staging, later attn_out)
// scratch: 8 waves x 2560 ushorts @ 16896   (per-wave private transpose buf)
//   q/k/probs view: [64][40]  row-major, b128-aligned rows (80 B)
//   vT view:        [32][72]  row-major (144 B rows)
#define XB_OFF 0
#define SCR_OFF 16896
#define LDS_TOT 37376   // ushorts = 74752 B  -> 2 WG/CU
#define STX 264
#define ST40 40
#define ST72 72

static __device__ __forceinline__ unsigned short f2b(float f) {
  union { float f; unsigned u; } v; v.f = f;
  unsigned r = v.u + 0x7FFFu + ((v.u >> 16) & 1u);  // RNE
  return (unsigned short)(r >> 16);
}

// ---------------- prep: W -> bf16 B-fragment layout ----------------
// Wf[(nt*8+ks)*64 + lane][j] = bf16( W[ks*32 + (lane>>4)*8 + j][colmap(nt, lane)] )
// qkv==0: colmap = nt*16 + (l&15)                       (Wm: direct)
// qkv==1: nt -> wave wv=nt/6, tt=nt%6: matrix m=tt>>1, sub=tt&1
//         colmap = m*256 + wv*32 + sub*16 + (l&15)      (Wqkv: per-head-wave order)
__global__ void prep_w_kernel(const float* __restrict__ W, unsigned short* __restrict__ Wf,
                              int ncols, int total, int qkv) {
  const int tid = blockIdx.x * blockDim.x + threadIdx.x;
  if (tid >= total) return;
  const int l  = tid & 63;
  const int ks = (tid >> 6) & 7;
  const int nt = tid >> 9;
  int col;
  if (qkv) {
    const int wv = nt / 6, tt = nt % 6;
    col = (tt >> 1) * 256 + wv * 32 + (tt & 1) * 16 + (l & 15);
  } else {
    col = nt * 16 + (l & 15);
  }
  const int k0 = ks * 32 + (l >> 4) * 8;
  short8 v;
#pragma unroll
  for (int j = 0; j < 8; ++j) v[j] = (short)f2b(W[(size_t)(k0 + j) * ncols + col]);
  *reinterpret_cast<short8*>(&Wf[(size_t)tid * 8]) = v;
}

// ---------------- prep: bias_table[rel_index] -> C-fragment layout ----------------
__global__ void prep_bias_kernel(const float* __restrict__ bt, const int* __restrict__ ri,
                                 float* __restrict__ bc) {
  const int tid = blockIdx.x * blockDim.x + threadIdx.x;
  if (tid >= 8192) return;
  const int l  = tid & 63;
  const int t  = (tid >> 6) & 15;
  const int h  = tid >> 10;
  const int mt = t >> 2, nt = t & 3;
  f32x4 v;
#pragma unroll
  for (int i = 0; i < 4; ++i) {
    const int r = mt * 16 + (l >> 4) * 4 + i;
    const int c = nt * 16 + (l & 15);
    v[i] = bt[ri[r * 64 + c] * 8 + h];
  }
  *reinterpret_cast<f32x4*>(&bc[(size_t)tid * 4]) = v;
}

// ---------------- main: one workgroup per window, wave w = head w ----------------
__global__ __launch_bounds__(512, 4)
void win_attn_kernel(const float* __restrict__ x,
                     const float* __restrict__ bqkv,
                     const float* __restrict__ bm,
                     const unsigned short* __restrict__ Wqkv_f,
                     const unsigned short* __restrict__ Wm_f,
                     const float* __restrict__ bias_c,
                     float* __restrict__ out)
{
  __shared__ unsigned short sm[LDS_TOT];
  const int tid = threadIdx.x;
  const int w   = tid >> 6;   // wave id == head id
  const int l   = tid & 63;
  const int lr  = l & 15;
  const int lg  = l >> 4;
  const long long win = blockIdx.x;
  const float* xw = x + win * (P_TOK * D_FEAT);
  const int SW = SCR_OFF + w * 2560;  // per-wave scratch base (ushorts)

  // ---- stage x -> bf16 LDS [64][264] ----
#pragma unroll
  for (int it = 0; it < 8; ++it) {
    const int f = it * 2048 + tid * 4;
    const int row = f >> 8, col = f & 255;
    const float4 v = *reinterpret_cast<const float4*>(xw + f);
    ushort4 b;
    b.x = f2b(v.x); b.y = f2b(v.y); b.z = f2b(v.z); b.w = f2b(v.w);
    *reinterpret_cast<ushort4*>(&sm[XB_OFF + row * STX + col]) = b;
  }
  __syncthreads();

  // ---- phase A: wave w computes q,k,v for head w (cols w*32..w*32+32 of each) ----
  short8 qf[4], kf[4], vf[2][2];
#pragma unroll
  for (int m = 0; m < 3; ++m) {
    f32x4 acc[4][2];
    {
      float bb0 = bqkv[m * 256 + w * 32 + lr];
      float bb1 = bqkv[m * 256 + w * 32 + 16 + lr];
#pragma unroll
      for (int mt = 0; mt < 4; ++mt) {
        acc[mt][0] = (f32x4){bb0, bb0, bb0, bb0};
        acc[mt][1] = (f32x4){bb1, bb1, bb1, bb1};
      }
    }
#pragma unroll
    for (int ks = 0; ks < 8; ++ks) {
      short8 a[4];
#pragma unroll
      for (int mt = 0; mt < 4; ++mt)
        a[mt] = *reinterpret_cast<const short8*>(
            &sm[XB_OFF + (lr + 16 * mt) * STX + lg * 8 + ks * 32]);
#pragma unroll
      for (int sub = 0; sub < 2; ++sub) {
        const short8 bf = *reinterpret_cast<const short8*>(
            &Wqkv_f[(size_t)(((w * 6 + m * 2 + sub) * 8 + ks) * 64 + l) * 8]);
#pragma unroll
        for (int mt = 0; mt < 4; ++mt)
          acc[mt][sub] = __builtin_amdgcn_mfma_f32_16x16x32_bf16(a[mt], bf, acc[mt][sub], 0, 0, 0);
      }
    }

    if (m == 2) {
      // vT scratch [d=32][tok 64+pad], packed ushort4 writes (wave-private)
#pragma unroll
      for (int sub = 0; sub < 2; ++sub)
#pragma unroll
        for (int mt = 0; mt < 4; ++mt) {
          ushort4 b;
          b.x = f2b(acc[mt][sub][0]); b.y = f2b(acc[mt][sub][1]);
          b.z = f2b(acc[mt][sub][2]); b.w = f2b(acc[mt][sub][3]);
          *reinterpret_cast<ushort4*>(&sm[SW + (sub * 16 + lr) * ST72 + 16 * mt + 4 * lg]) = b;
        }
      // B-frags for PV: lane holds col d=lr+16nt, tokens kh*32+lg*8..+8
#pragma unroll
      for (int nt = 0; nt < 2; ++nt)
#pragma unroll
        for (int kh = 0; kh < 2; ++kh)
          vf[nt][kh] = *reinterpret_cast<const short8*>(
              &sm[SW + (lr + 16 * nt) * ST72 + kh * 32 + lg * 8]);
    } else {
      // q/k scratch [tok 64][d 32+pad] row-major, then aligned b128 frag reads
      const float sc = (m == 1) ? 0.0625f : 1.0f;
#pragma unroll
      for (int sub = 0; sub < 2; ++sub)
#pragma unroll
        for (int mt = 0; mt < 4; ++mt)
#pragma unroll
          for (int i = 0; i < 4; ++i)
            sm[SW + (16 * mt + 4 * lg + i) * ST40 + sub * 16 + lr] = f2b(acc[mt][sub][i] * sc);
#pragma unroll
      for (int mt = 0; mt < 4; ++mt) {
        const short8 fr = *reinterpret_cast<const short8*>(
            &sm[SW + (lr + 16 * mt) * ST40 + lg * 8]);
        if (m == 0) qf[mt] = fr; else kf[mt] = fr;
      }
    }
  }

  // ---- scores (+bias), in-register softmax ----
  f32x4 s[4][4];
#pragma unroll
  for (int mt = 0; mt < 4; ++mt)
#pragma unroll
    for (int nt = 0; nt < 4; ++nt) {
      const f32x4 bb = *reinterpret_cast<const f32x4*>(
          &bias_c[(size_t)((w * 16 + mt * 4 + nt) * 64 + l) * 4]);
      s[mt][nt] = __builtin_amdgcn_mfma_f32_16x16x32_bf16(qf[mt], kf[nt], bb, 0, 0, 0);
    }
#pragma unroll
  for (int mt = 0; mt < 4; ++mt)
#pragma unroll
    for (int i = 0; i < 4; ++i) {
      float mx = fmaxf(fmaxf(s[mt][0][i], s[mt][1][i]), fmaxf(s[mt][2][i], s[mt][3][i]));
      mx = fmaxf(mx, __shfl_xor(mx, 1));
      mx = fmaxf(mx, __shfl_xor(mx, 2));
      mx = fmaxf(mx, __shfl_xor(mx, 4));
      mx = fmaxf(mx, __shfl_xor(mx, 8));
      float e0 = __expf(s[mt][0][i] - mx);
      float e1 = __expf(s[mt][1][i] - mx);
      float e2 = __expf(s[mt][2][i] - mx);
      float e3 = __expf(s[mt][3][i] - mx);
      float sum = e0 + e1 + e2 + e3;
      sum += __shfl_xor(sum, 1);
      sum += __shfl_xor(sum, 2);
      sum += __shfl_xor(sum, 4);
      sum += __shfl_xor(sum, 8);
      const float rinv = 1.0f / sum;
      s[mt][0][i] = e0 * rinv; s[mt][1][i] = e1 * rinv;
      s[mt][2][i] = e2 * rinv; s[mt][3][i] = e3 * rinv;
    }

  // ---- PV via wave-private probs transpose, two 32-col halves ----
  f32x4 o[4][2];
#pragma unroll
  for (int mt = 0; mt < 4; ++mt)
#pragma unroll
    for (int nt = 0; nt < 2; ++nt)
      o[mt][nt] = (f32x4){0.f, 0.f, 0.f, 0.f};
#pragma unroll
  for (int kh = 0; kh < 2; ++kh) {
#pragma unroll
    for (int ntl = 0; ntl < 2; ++ntl)
#pragma unroll
      for (int mt = 0; mt < 4; ++mt)
#pragma unroll
        for (int i = 0; i < 4; ++i)
          sm[SW + (16 * mt + 4 * lg + i) * ST40 + ntl * 16 + lr] = f2b(s[mt][2 * kh + ntl][i]);
#pragma unroll
    for (int mt = 0; mt < 4; ++mt) {
      const short8 pa = *reinterpret_cast<const short8*>(
          &sm[SW + (lr + 16 * mt) * ST40 + lg * 8]);
#pragma unroll
      for (int nt = 0; nt < 2; ++nt)
        o[mt][nt] = __builtin_amdgcn_mfma_f32_16x16x32_bf16(pa, vf[nt][kh], o[mt][nt], 0, 0, 0);
    }
  }

  // ---- attn_out -> xb region (needs all waves done reading xb) ----
  __syncthreads();
#pragma unroll
  for (int mt = 0; mt < 4; ++mt)
#pragma unroll
    for (int nt = 0; nt < 2; ++nt)
#pragma unroll
      for (int i = 0; i < 4; ++i)
        sm[XB_OFF + (16 * mt + 4 * lg + i) * STX + w * 32 + nt * 16 + lr] = f2b(o[mt][nt][i]);
  __syncthreads();

  // ---- phase C: out = attn_out @ Wm + bm; wave w owns cols [32w, 32w+32) ----
  f32x4 po[4][2];
  {
    float bm0 = bm[w * 32 + lr];
    float bm1 = bm[w * 32 + 16 + lr];
#pragma unroll
    for (int mt = 0; mt < 4; ++mt) {
      po[mt][0] = (f32x4){bm0, bm0, bm0, bm0};
      po[mt][1] = (f32x4){bm1, bm1, bm1, bm1};
    }
  }
#pragma unroll
  for (int ks = 0; ks < 8; ++ks) {
    short8 a[4];
#pragma unroll
    for (int mt = 0; mt < 4; ++mt)
      a[mt] = *reinterpret_cast<const short8*>(
          &sm[XB_OFF + (lr + 16 * mt) * STX + lg * 8 + ks * 32]);
#pragma unroll
    for (int nt = 0; nt < 2; ++nt) {
      const short8 bf = *reinterpret_cast<const short8*>(
          &Wm_f[(size_t)(((w * 2 + nt) * 8 + ks) * 64 + l) * 8]);
#pragma unroll
      for (int mt = 0; mt < 4; ++mt)
        po[mt][nt] = __builtin_amdgcn_mfma_f32_16x16x32_bf16(a[mt], bf, po[mt][nt], 0, 0, 0);
    }
  }

  float* ow = out + win * (P_TOK * D_FEAT);
#pragma unroll
  for (int mt = 0; mt < 4; ++mt)
#pragma unroll
    for (int nt = 0; nt < 2; ++nt)
#pragma unroll
      for (int i = 0; i < 4; ++i)
        ow[(16 * mt + 4 * lg + i) * 256 + w * 32 + nt * 16 + lr] = po[mt][nt][i];
}

extern "C" void kernel_launch(void* const* d_in, const int* in_sizes, int n_in,
                              void* d_out, int out_size, void* d_ws, size_t ws_size,
                              hipStream_t stream) {
  const float* x    = (const float*)d_in[0];
  const float* Wqkv = (const float*)d_in[1];
  const float* bqkv = (const float*)d_in[2];
  const float* Wm   = (const float*)d_in[3];
  const float* bm   = (const float*)d_in[4];
  const float* bt   = (const float*)d_in[5];
  const int*   ri   = (const int*)d_in[6];

  // workspace layout: Wqkv_f 393216 B | Wm_f 131072 B | bias_c 131072 B
  unsigned short* Wqkv_f = (unsigned short*)d_ws;
  unsigned short* Wm_f   = (unsigned short*)((char*)d_ws + 393216);
  float*          bias_c = (float*)((char*)d_ws + 524288);

  prep_w_kernel<<<48, 512, 0, stream>>>(Wqkv, Wqkv_f, 768, 24576, 1);
  prep_w_kernel<<<16, 512, 0, stream>>>(Wm, Wm_f, 256, 8192, 0);
  prep_bias_kernel<<<16, 512, 0, stream>>>(bt, ri, bias_c);

  const int nwin = in_sizes[0] / (P_TOK * D_FEAT);  // 4096
  win_attn_kernel<<<nwin, 512, 0, stream>>>(x, bqkv, bm, Wqkv_f, Wm_f, bias_c, (float*)d_out);
}